// Round 4
// baseline (6480.228 us; speedup 1.0000x reference)
//
#include <hip/hip_runtime.h>
#include <math.h>

#define N_TOK 2048
#define DIM   1024
#define D3    3072
#define NHEAD 16
#define DH    64
#define TT    512
#define HID   4096
#define NEXP  8

__device__ __forceinline__ float gelu_f(float x){
  const float c = 0.7978845608028654f; // sqrt(2/pi)
  float t = tanhf(c * (x + 0.044715f * x * x * x));
  return 0.5f * x * (1.0f + t);
}

// ---------------- LayerNorm: f32 in, f32 out (one block per token) --------
__global__ __launch_bounds__(256) void ln_k(const float* __restrict__ xin,
                                            const float* __restrict__ w,
                                            const float* __restrict__ b,
                                            float* __restrict__ out){
  int tok = blockIdx.x;
  int t = threadIdx.x;
  float vals[4]; float s = 0.f, ss = 0.f;
#pragma unroll
  for (int i = 0; i < 4; i++){
    int d = t + i * 256;
    float v = xin[(size_t)tok * DIM + d];
    vals[i] = v; s += v; ss += v * v;
  }
  __shared__ float rs[256], rq[256];
  rs[t] = s; rq[t] = ss; __syncthreads();
  for (int k = 128; k > 0; k >>= 1){
    if (t < k){ rs[t] += rs[t + k]; rq[t] += rq[t + k]; }
    __syncthreads();
  }
  float mu  = rs[0] * (1.0f / DIM);
  float var = rq[0] * (1.0f / DIM) - mu * mu;
  float inv = rsqrtf(var + 1e-5f);
#pragma unroll
  for (int i = 0; i < 4; i++){
    int d = t + i * 256;
    out[(size_t)tok * DIM + d] = (vals[i] - mu) * inv * w[d] + b[d];
  }
}

// ------- Tiled GEMM (all f32): C[M,N] = A[M,K] @ B[K,N] + bias ------------
// EPI 0: Cf = v                 (qkv)
// EPI 1: Cf = gelu(v)           (expert h1)
// EPI 2: Cf += rowscale[m*8]*v  (expert combine)
// EPI 3: Cf = v + Res[m,n]      (out-proj + residual)
#define BM 128
#define BN 128
#define BKK 16

template<int EPI>
__global__ __launch_bounds__(256) void gemm128(
    const float* __restrict__ A, const float* __restrict__ Bm,
    const float* __restrict__ bias,
    float* __restrict__ Cf,
    const float* __restrict__ Res, const float* __restrict__ rowscale,
    int M, int Nn, int K)
{
  __shared__ float As[BKK][BM + 4];
  __shared__ float Bs[BKK][BN + 4];
  int bn = blockIdx.x * BN, bm = blockIdx.y * BM;
  int t = threadIdx.x;
  int tx = t & 15, ty = t >> 4;
  int arow = t >> 1, acol = (t & 1) * 8;
  int brow = t >> 4, bcol = (t & 15) * 8;
  const float* Ap = A + (size_t)(bm + arow) * K + acol;
  const float* Bp = Bm + (size_t)brow * Nn + bn + bcol;
  float acc[8][8] = {};
  for (int k0 = 0; k0 < K; k0 += BKK){
    float4 av0 = *(const float4*)Ap;
    float4 av1 = *(const float4*)(Ap + 4);
    float4 bv0 = *(const float4*)Bp;
    float4 bv1 = *(const float4*)(Bp + 4);
    Ap += BKK; Bp += (size_t)BKK * Nn;
    float af[8] = {av0.x,av0.y,av0.z,av0.w,av1.x,av1.y,av1.z,av1.w};
#pragma unroll
    for (int i = 0; i < 8; i++) As[acol + i][arow] = af[i];
    float bf[8] = {bv0.x,bv0.y,bv0.z,bv0.w,bv1.x,bv1.y,bv1.z,bv1.w};
#pragma unroll
    for (int i = 0; i < 8; i++) Bs[brow][bcol + i] = bf[i];
    __syncthreads();
#pragma unroll
    for (int k = 0; k < BKK; k++){
      float4 a0 = *(const float4*)&As[k][ty * 4];
      float4 a1 = *(const float4*)&As[k][64 + ty * 4];
      float4 b0 = *(const float4*)&Bs[k][tx * 4];
      float4 b1 = *(const float4*)&Bs[k][64 + tx * 4];
      float ar[8] = {a0.x,a0.y,a0.z,a0.w,a1.x,a1.y,a1.z,a1.w};
      float br[8] = {b0.x,b0.y,b0.z,b0.w,b1.x,b1.y,b1.z,b1.w};
#pragma unroll
      for (int i = 0; i < 8; i++)
#pragma unroll
        for (int j = 0; j < 8; j++)
          acc[i][j] += ar[i] * br[j];
    }
    __syncthreads();
  }
#pragma unroll
  for (int i = 0; i < 8; i++){
    int m = bm + ((i < 4) ? (ty * 4 + i) : (64 + ty * 4 + i - 4));
    float rsv = (EPI == 2) ? rowscale[(size_t)m * NEXP] : 0.f;
#pragma unroll
    for (int j = 0; j < 8; j++){
      int n = bn + ((j < 4) ? (tx * 4 + j) : (64 + tx * 4 + j - 4));
      size_t idx = (size_t)m * Nn + n;
      float v = acc[i][j] + bias[n];
      if (EPI == 0)      Cf[idx] = v;
      else if (EPI == 1) Cf[idx] = gelu_f(v);
      else if (EPI == 2) Cf[idx] += rsv * v;
      else               Cf[idx] = v + Res[idx];
    }
  }
}

// ---------------- Attention scores: S[bh,q,k] = (Q·K)/8 -------------------
__global__ __launch_bounds__(256) void scores_k(const float* __restrict__ qkv,
                                                float* __restrict__ S){
  int bh = blockIdx.z; int b = bh >> 4, h = bh & 15;
  int q0 = blockIdx.y * 64, k0 = blockIdx.x * 64;
  __shared__ float Qs[64][68];   // [d][q]
  __shared__ float Ks[64][68];   // [d][k]
  int t = threadIdx.x;
  int r = t >> 2, dp = (t & 3) * 16;
  {
    const float* qp = qkv + (size_t)(b * TT + q0 + r) * D3 + h * DH + dp;
    const float* kp = qkv + (size_t)(b * TT + k0 + r) * D3 + DIM + h * DH + dp;
#pragma unroll
    for (int c = 0; c < 4; c++){
      float4 qv = *(const float4*)(qp + c * 4);
      float4 kv = *(const float4*)(kp + c * 4);
      Qs[dp + c*4 + 0][r] = qv.x; Qs[dp + c*4 + 1][r] = qv.y;
      Qs[dp + c*4 + 2][r] = qv.z; Qs[dp + c*4 + 3][r] = qv.w;
      Ks[dp + c*4 + 0][r] = kv.x; Ks[dp + c*4 + 1][r] = kv.y;
      Ks[dp + c*4 + 2][r] = kv.z; Ks[dp + c*4 + 3][r] = kv.w;
    }
  }
  __syncthreads();
  int tx = t & 15, ty = t >> 4;
  float acc[4][4] = {};
#pragma unroll 8
  for (int d = 0; d < 64; d++){
    float4 qv = *(const float4*)&Qs[d][ty * 4];
    float4 kv = *(const float4*)&Ks[d][tx * 4];
    float qa[4] = {qv.x,qv.y,qv.z,qv.w};
    float ka[4] = {kv.x,kv.y,kv.z,kv.w};
#pragma unroll
    for (int i = 0; i < 4; i++)
#pragma unroll
      for (int j = 0; j < 4; j++)
        acc[i][j] += qa[i] * ka[j];
  }
#pragma unroll
  for (int i = 0; i < 4; i++)
#pragma unroll
    for (int j = 0; j < 4; j++)
      S[((size_t)bh * TT + q0 + ty*4 + i) * TT + k0 + tx*4 + j] = acc[i][j] * 0.125f;
}

// ---------------- Softmax over rows of 512 --------------------------------
__global__ __launch_bounds__(256) void softmax_k(float* __restrict__ S){
  size_t row = blockIdx.x;
  float* p = S + row * TT;
  int t = threadIdx.x;
  float v0 = p[t], v1 = p[t + 256];
  __shared__ float red[256];
  red[t] = fmaxf(v0, v1); __syncthreads();
  for (int k = 128; k > 0; k >>= 1){ if (t < k) red[t] = fmaxf(red[t], red[t + k]); __syncthreads(); }
  float m = red[0]; __syncthreads();
  float e0 = expf(v0 - m), e1 = expf(v1 - m);
  red[t] = e0 + e1; __syncthreads();
  for (int k = 128; k > 0; k >>= 1){ if (t < k) red[t] += red[t + k]; __syncthreads(); }
  float inv = 1.0f / red[0];
  p[t] = e0 * inv; p[t + 256] = e1 * inv;
}

// ---------------- ctx = P @ V, token-major [2048,1024], f32 ---------------
__global__ __launch_bounds__(256) void ctx_k(const float* __restrict__ P,
                                             const float* __restrict__ qkv,
                                             float* __restrict__ ctx){
  int bh = blockIdx.y; int b = bh >> 4, h = bh & 15;
  int q0 = blockIdx.x * 64;
  __shared__ float Ps[16][68];   // [k][q]
  __shared__ float Vs[16][68];   // [k][d]
  int t = threadIdx.x;
  int tx = t & 15, ty = t >> 4;
  int pq = t >> 2, pk = (t & 3) * 4;
  int vk = t >> 4, vd = (t & 15) * 4;
  float acc[4][4] = {};
  for (int kk = 0; kk < TT; kk += 16){
    float4 pv = *(const float4*)&P[((size_t)bh * TT + q0 + pq) * TT + kk + pk];
    Ps[pk + 0][pq] = pv.x; Ps[pk + 1][pq] = pv.y;
    Ps[pk + 2][pq] = pv.z; Ps[pk + 3][pq] = pv.w;
    float4 vv = *(const float4*)&qkv[(size_t)(b * TT + kk + vk) * D3 + 2 * DIM + h * DH + vd];
    Vs[vk][vd + 0] = vv.x; Vs[vk][vd + 1] = vv.y;
    Vs[vk][vd + 2] = vv.z; Vs[vk][vd + 3] = vv.w;
    __syncthreads();
#pragma unroll
    for (int k = 0; k < 16; k++){
      float4 a = *(const float4*)&Ps[k][ty * 4];
      float4 bb = *(const float4*)&Vs[k][tx * 4];
      float aa[4] = {a.x,a.y,a.z,a.w};
      float bv[4] = {bb.x,bb.y,bb.z,bb.w};
#pragma unroll
      for (int i = 0; i < 4; i++)
#pragma unroll
        for (int j = 0; j < 4; j++)
          acc[i][j] += aa[i] * bv[j];
    }
    __syncthreads();
  }
#pragma unroll
  for (int i = 0; i < 4; i++)
#pragma unroll
    for (int j = 0; j < 4; j++)
      ctx[(size_t)(b * TT + q0 + ty*4 + i) * DIM + h * DH + tx*4 + j] = acc[i][j];
}

// -------- Gate from exact f32 ln2: softmax + top-2 renorm weights ---------
__global__ __launch_bounds__(256) void gate_k(const float* __restrict__ ln2f,
                                              const float* __restrict__ wg,
                                              float* __restrict__ we){
  int tok = blockIdx.x * 4 + (threadIdx.x >> 6);
  int lane = threadIdx.x & 63;
  float acc[8] = {};
  for (int d = lane; d < DIM; d += 64){
    float x = ln2f[(size_t)tok * DIM + d];
    float4 w0 = *(const float4*)&wg[d * 8];
    float4 w1v = *(const float4*)&wg[d * 8 + 4];
    float wv[8] = {w0.x,w0.y,w0.z,w0.w,w1v.x,w1v.y,w1v.z,w1v.w};
#pragma unroll
    for (int e = 0; e < 8; e++) acc[e] += x * wv[e];
  }
#pragma unroll
  for (int off = 32; off > 0; off >>= 1){
#pragma unroll
    for (int e = 0; e < 8; e++) acc[e] += __shfl_down(acc[e], off);
  }
  if (lane == 0){
    float m = acc[0];
    for (int e = 1; e < 8; e++) m = fmaxf(m, acc[e]);
    float pr[8], s = 0.f;
    for (int e = 0; e < 8; e++){ pr[e] = expf(acc[e] - m); s += pr[e]; }
    for (int e = 0; e < 8; e++) pr[e] /= s;
    int i0 = 0;
    for (int e = 1; e < 8; e++) if (pr[e] > pr[i0]) i0 = e;
    int i1 = (i0 == 0) ? 1 : 0;
    for (int e = 0; e < 8; e++) if (e != i0 && pr[e] > pr[i1]) i1 = e;
    float sm = pr[i0] + pr[i1];
    for (int e = 0; e < 8; e++)
      we[(size_t)tok * 8 + e] = (e == i0) ? pr[i0] / sm : ((e == i1) ? pr[i1] / sm : 0.f);
  }
}

// ---------------- Final: out = h + moe_acc (f32) --------------------------
__global__ __launch_bounds__(256) void final_k(const float* __restrict__ h,
                                               const float* __restrict__ acc,
                                               float* __restrict__ out){
  size_t i = (size_t)blockIdx.x * 256 + threadIdx.x;
  out[i] = h[i] + acc[i];
}

extern "C" void kernel_launch(void* const* d_in, const int* in_sizes, int n_in,
                              void* d_out, int out_size, void* d_ws, size_t ws_size,
                              hipStream_t stream){
  const float* x     = (const float*)d_in[0];
  const float* ln1w  = (const float*)d_in[1];
  const float* ln1b  = (const float*)d_in[2];
  const float* ln2w  = (const float*)d_in[3];
  const float* ln2b  = (const float*)d_in[4];
  const float* wqkv  = (const float*)d_in[5];
  const float* bqkv  = (const float*)d_in[6];
  const float* wo    = (const float*)d_in[7];
  const float* bo    = (const float*)d_in[8];
  const float* wgate = (const float*)d_in[9];
  const float* w1    = (const float*)d_in[10];
  const float* b1    = (const float*)d_in[11];
  const float* w2    = (const float*)d_in[12];
  const float* b2    = (const float*)d_in[13];

  // Workspace layout (f32, with aliasing):
  //   [0,   8M)   ln1  -> later accb   (ln1 dead after qkv GEMM)
  //   [8M,  32M)  qkv                  (dead after ctx_k)
  //   [32M, 40M)  ctx                  (dead after out-proj)
  //   [40M, 48M)  hbuf                 (live to end)
  //   [48M, 56M)  ln2f                 (live through experts)
  //   [56M, 57M)  webuf
  //   [57M, 121M) sc  -> later h1      (sc dead after ctx_k)
  char* ws = (char*)d_ws;
  const size_t MB = 1024 * 1024;
  float* ln1   = (float*)(ws + 0 * MB);
  float* accb  = (float*)(ws + 0 * MB);
  float* qkv   = (float*)(ws + 8 * MB);
  float* ctx   = (float*)(ws + 32 * MB);
  float* hbuf  = (float*)(ws + 40 * MB);
  float* ln2f  = (float*)(ws + 48 * MB);
  float* webuf = (float*)(ws + 56 * MB);
  float* sc    = (float*)(ws + 57 * MB);
  float* h1    = (float*)(ws + 57 * MB);

  // 1. ln1 = LN(x)
  ln_k<<<N_TOK, 256, 0, stream>>>(x, ln1w, ln1b, ln1);
  // 2. qkv = ln1 @ w_qkv + b_qkv
  gemm128<0><<<dim3(D3 / BN, N_TOK / BM), 256, 0, stream>>>(
      ln1, wqkv, bqkv, qkv, nullptr, nullptr, N_TOK, D3, DIM);
  // 3. scores
  scores_k<<<dim3(8, 8, 64), 256, 0, stream>>>(qkv, sc);
  // 4. softmax
  softmax_k<<<64 * TT, 256, 0, stream>>>(sc);
  // 5. ctx = P @ V
  ctx_k<<<dim3(8, 64), 256, 0, stream>>>(sc, qkv, ctx);
  // 6. h = ctx @ w_o + b_o + x
  gemm128<3><<<dim3(DIM / BN, N_TOK / BM), 256, 0, stream>>>(
      ctx, wo, bo, hbuf, x, nullptr, N_TOK, DIM, DIM);
  // 7. ln2 = LN(h)
  ln_k<<<N_TOK, 256, 0, stream>>>(hbuf, ln2w, ln2b, ln2f);
  // 8. gate weights (f32 end-to-end: selection matches numpy)
  gate_k<<<N_TOK / 4, 256, 0, stream>>>(ln2f, wgate, webuf);
  // 9. MoE (dense, reference-faithful)
  hipMemsetAsync(accb, 0, (size_t)N_TOK * DIM * 4, stream);
  for (int e = 0; e < NEXP; e++){
    gemm128<1><<<dim3(HID / BN, N_TOK / BM), 256, 0, stream>>>(
        ln2f, w1 + (size_t)e * DIM * HID, b1 + (size_t)e * HID,
        h1, nullptr, nullptr, N_TOK, HID, DIM);
    gemm128<2><<<dim3(DIM / BN, N_TOK / BM), 256, 0, stream>>>(
        h1, w2 + (size_t)e * HID * DIM, b2 + (size_t)e * DIM,
        accb, nullptr, webuf + e, N_TOK, DIM, HID);
  }
  // 10. out = h + moe
  final_k<<<(N_TOK * DIM) / 256, 256, 0, stream>>>(hbuf, accb, (float*)d_out);
}

// Round 5
// 2093.183 us; speedup vs baseline: 3.0959x; 3.0959x over previous
//
#include <hip/hip_runtime.h>
#include <math.h>

typedef unsigned short ushort_t;
using short8 = __attribute__((ext_vector_type(8))) short;
using f32x4  = __attribute__((ext_vector_type(4))) float;

#define N_TOK 2048
#define DIM   1024
#define D3    3072
#define NHEAD 16
#define DH    64
#define TT    512
#define HID   4096
#define NEXP  8

__device__ __forceinline__ float bf2f(ushort_t u){
  union { unsigned int i; float f; } x; x.i = ((unsigned int)u) << 16; return x.f;
}
__device__ __forceinline__ ushort_t f2bf(float f){
  union { unsigned int i; float f; } x; x.f = f;
  unsigned int r = x.i + 0x7fffu + ((x.i >> 16) & 1u);
  return (ushort_t)(r >> 16);
}
__device__ __forceinline__ float gelu_f(float x){
  const float c = 0.7978845608028654f; // sqrt(2/pi)
  float t = tanhf(c * (x + 0.044715f * x * x * x));
  return 0.5f * x * (1.0f + t);
}

// ------- LayerNorm: f32 in, f32 out (+ optional bf16 copy) ----------------
template<bool WB>
__global__ __launch_bounds__(256) void ln_k(const float* __restrict__ xin,
                                            const float* __restrict__ w,
                                            const float* __restrict__ b,
                                            float* __restrict__ out,
                                            ushort_t* __restrict__ outbf){
  int tok = blockIdx.x;
  int t = threadIdx.x;
  float vals[4]; float s = 0.f, ss = 0.f;
#pragma unroll
  for (int i = 0; i < 4; i++){
    int d = t + i * 256;
    float v = xin[(size_t)tok * DIM + d];
    vals[i] = v; s += v; ss += v * v;
  }
  __shared__ float rs[256], rq[256];
  rs[t] = s; rq[t] = ss; __syncthreads();
  for (int k = 128; k > 0; k >>= 1){
    if (t < k){ rs[t] += rs[t + k]; rq[t] += rq[t + k]; }
    __syncthreads();
  }
  float mu  = rs[0] * (1.0f / DIM);
  float var = rq[0] * (1.0f / DIM) - mu * mu;
  float inv = rsqrtf(var + 1e-5f);
#pragma unroll
  for (int i = 0; i < 4; i++){
    int d = t + i * 256;
    float r = (vals[i] - mu) * inv * w[d] + b[d];
    out[(size_t)tok * DIM + d] = r;
    if (WB) outbf[(size_t)tok * DIM + d] = f2bf(r);
  }
}

// ------- f32 tiled GEMM (attention path; EPI 0 plain, 3 +residual) --------
#define BM 128
#define BN 128
#define BKK 16

template<int EPI>
__global__ __launch_bounds__(256) void gemm128(
    const float* __restrict__ A, const float* __restrict__ Bm,
    const float* __restrict__ bias,
    float* __restrict__ Cf,
    const float* __restrict__ Res,
    int M, int Nn, int K)
{
  __shared__ float As[BKK][BM + 4];
  __shared__ float Bs[BKK][BN + 4];
  int bn = blockIdx.x * BN, bm = blockIdx.y * BM;
  int t = threadIdx.x;
  int tx = t & 15, ty = t >> 4;
  int arow = t >> 1, acol = (t & 1) * 8;
  int brow = t >> 4, bcol = (t & 15) * 8;
  const float* Ap = A + (size_t)(bm + arow) * K + acol;
  const float* Bp = Bm + (size_t)brow * Nn + bn + bcol;
  float acc[8][8] = {};
  for (int k0 = 0; k0 < K; k0 += BKK){
    float4 av0 = *(const float4*)Ap;
    float4 av1 = *(const float4*)(Ap + 4);
    float4 bv0 = *(const float4*)Bp;
    float4 bv1 = *(const float4*)(Bp + 4);
    Ap += BKK; Bp += (size_t)BKK * Nn;
    float af[8] = {av0.x,av0.y,av0.z,av0.w,av1.x,av1.y,av1.z,av1.w};
#pragma unroll
    for (int i = 0; i < 8; i++) As[acol + i][arow] = af[i];
    float bf[8] = {bv0.x,bv0.y,bv0.z,bv0.w,bv1.x,bv1.y,bv1.z,bv1.w};
#pragma unroll
    for (int i = 0; i < 8; i++) Bs[brow][bcol + i] = bf[i];
    __syncthreads();
#pragma unroll
    for (int k = 0; k < BKK; k++){
      float4 a0 = *(const float4*)&As[k][ty * 4];
      float4 a1 = *(const float4*)&As[k][64 + ty * 4];
      float4 b0 = *(const float4*)&Bs[k][tx * 4];
      float4 b1 = *(const float4*)&Bs[k][64 + tx * 4];
      float ar[8] = {a0.x,a0.y,a0.z,a0.w,a1.x,a1.y,a1.z,a1.w};
      float br[8] = {b0.x,b0.y,b0.z,b0.w,b1.x,b1.y,b1.z,b1.w};
#pragma unroll
      for (int i = 0; i < 8; i++)
#pragma unroll
        for (int j = 0; j < 8; j++)
          acc[i][j] += ar[i] * br[j];
    }
    __syncthreads();
  }
#pragma unroll
  for (int i = 0; i < 8; i++){
    int m = bm + ((i < 4) ? (ty * 4 + i) : (64 + ty * 4 + i - 4));
#pragma unroll
    for (int j = 0; j < 8; j++){
      int n = bn + ((j < 4) ? (tx * 4 + j) : (64 + tx * 4 + j - 4));
      size_t idx = (size_t)m * Nn + n;
      float v = acc[i][j] + bias[n];
      if (EPI == 0) Cf[idx] = v;
      else          Cf[idx] = v + Res[idx];
    }
  }
}

// ---------------- Attention scores: S[bh,q,k] = (Q·K)/8 -------------------
__global__ __launch_bounds__(256) void scores_k(const float* __restrict__ qkv,
                                                float* __restrict__ S){
  int bh = blockIdx.z; int b = bh >> 4, h = bh & 15;
  int q0 = blockIdx.y * 64, k0 = blockIdx.x * 64;
  __shared__ float Qs[64][68];
  __shared__ float Ks[64][68];
  int t = threadIdx.x;
  int r = t >> 2, dp = (t & 3) * 16;
  {
    const float* qp = qkv + (size_t)(b * TT + q0 + r) * D3 + h * DH + dp;
    const float* kp = qkv + (size_t)(b * TT + k0 + r) * D3 + DIM + h * DH + dp;
#pragma unroll
    for (int c = 0; c < 4; c++){
      float4 qv = *(const float4*)(qp + c * 4);
      float4 kv = *(const float4*)(kp + c * 4);
      Qs[dp + c*4 + 0][r] = qv.x; Qs[dp + c*4 + 1][r] = qv.y;
      Qs[dp + c*4 + 2][r] = qv.z; Qs[dp + c*4 + 3][r] = qv.w;
      Ks[dp + c*4 + 0][r] = kv.x; Ks[dp + c*4 + 1][r] = kv.y;
      Ks[dp + c*4 + 2][r] = kv.z; Ks[dp + c*4 + 3][r] = kv.w;
    }
  }
  __syncthreads();
  int tx = t & 15, ty = t >> 4;
  float acc[4][4] = {};
#pragma unroll 8
  for (int d = 0; d < 64; d++){
    float4 qv = *(const float4*)&Qs[d][ty * 4];
    float4 kv = *(const float4*)&Ks[d][tx * 4];
    float qa[4] = {qv.x,qv.y,qv.z,qv.w};
    float ka[4] = {kv.x,kv.y,kv.z,kv.w};
#pragma unroll
    for (int i = 0; i < 4; i++)
#pragma unroll
      for (int j = 0; j < 4; j++)
        acc[i][j] += qa[i] * ka[j];
  }
#pragma unroll
  for (int i = 0; i < 4; i++)
#pragma unroll
    for (int j = 0; j < 4; j++)
      S[((size_t)bh * TT + q0 + ty*4 + i) * TT + k0 + tx*4 + j] = acc[i][j] * 0.125f;
}

// ---------------- Softmax over rows of 512 --------------------------------
__global__ __launch_bounds__(256) void softmax_k(float* __restrict__ S){
  size_t row = blockIdx.x;
  float* p = S + row * TT;
  int t = threadIdx.x;
  float v0 = p[t], v1 = p[t + 256];
  __shared__ float red[256];
  red[t] = fmaxf(v0, v1); __syncthreads();
  for (int k = 128; k > 0; k >>= 1){ if (t < k) red[t] = fmaxf(red[t], red[t + k]); __syncthreads(); }
  float m = red[0]; __syncthreads();
  float e0 = expf(v0 - m), e1 = expf(v1 - m);
  red[t] = e0 + e1; __syncthreads();
  for (int k = 128; k > 0; k >>= 1){ if (t < k) red[t] += red[t + k]; __syncthreads(); }
  float inv = 1.0f / red[0];
  p[t] = e0 * inv; p[t + 256] = e1 * inv;
}

// ---------------- ctx = P @ V, token-major [2048,1024], f32 ---------------
__global__ __launch_bounds__(256) void ctx_k(const float* __restrict__ P,
                                             const float* __restrict__ qkv,
                                             float* __restrict__ ctx){
  int bh = blockIdx.y; int b = bh >> 4, h = bh & 15;
  int q0 = blockIdx.x * 64;
  __shared__ float Ps[16][68];
  __shared__ float Vs[16][68];
  int t = threadIdx.x;
  int tx = t & 15, ty = t >> 4;
  int pq = t >> 2, pk = (t & 3) * 4;
  int vk = t >> 4, vd = (t & 15) * 4;
  float acc[4][4] = {};
  for (int kk = 0; kk < TT; kk += 16){
    float4 pv = *(const float4*)&P[((size_t)bh * TT + q0 + pq) * TT + kk + pk];
    Ps[pk + 0][pq] = pv.x; Ps[pk + 1][pq] = pv.y;
    Ps[pk + 2][pq] = pv.z; Ps[pk + 3][pq] = pv.w;
    float4 vv = *(const float4*)&qkv[(size_t)(b * TT + kk + vk) * D3 + 2 * DIM + h * DH + vd];
    Vs[vk][vd + 0] = vv.x; Vs[vk][vd + 1] = vv.y;
    Vs[vk][vd + 2] = vv.z; Vs[vk][vd + 3] = vv.w;
    __syncthreads();
#pragma unroll
    for (int k = 0; k < 16; k++){
      float4 a = *(const float4*)&Ps[k][ty * 4];
      float4 bb = *(const float4*)&Vs[k][tx * 4];
      float aa[4] = {a.x,a.y,a.z,a.w};
      float bv[4] = {bb.x,bb.y,bb.z,bb.w};
#pragma unroll
      for (int i = 0; i < 4; i++)
#pragma unroll
        for (int j = 0; j < 4; j++)
          acc[i][j] += aa[i] * bv[j];
    }
    __syncthreads();
  }
#pragma unroll
  for (int i = 0; i < 4; i++)
#pragma unroll
    for (int j = 0; j < 4; j++)
      ctx[(size_t)(b * TT + q0 + ty*4 + i) * DIM + h * DH + tx*4 + j] = acc[i][j];
}

// -------- Gate (exact f32) + top-2 renorm weights -------------------------
__global__ __launch_bounds__(256) void gate_k(const float* __restrict__ ln2f,
                                              const float* __restrict__ wg,
                                              float* __restrict__ we){
  int tok = blockIdx.x * 4 + (threadIdx.x >> 6);
  int lane = threadIdx.x & 63;
  float acc[8] = {};
  for (int d = lane; d < DIM; d += 64){
    float x = ln2f[(size_t)tok * DIM + d];
    float4 w0 = *(const float4*)&wg[d * 8];
    float4 w1v = *(const float4*)&wg[d * 8 + 4];
    float wv[8] = {w0.x,w0.y,w0.z,w0.w,w1v.x,w1v.y,w1v.z,w1v.w};
#pragma unroll
    for (int e = 0; e < 8; e++) acc[e] += x * wv[e];
  }
#pragma unroll
  for (int off = 32; off > 0; off >>= 1){
#pragma unroll
    for (int e = 0; e < 8; e++) acc[e] += __shfl_down(acc[e], off);
  }
  if (lane == 0){
    float m = acc[0];
    for (int e = 1; e < 8; e++) m = fmaxf(m, acc[e]);
    float pr[8], s = 0.f;
    for (int e = 0; e < 8; e++){ pr[e] = expf(acc[e] - m); s += pr[e]; }
    for (int e = 0; e < 8; e++) pr[e] /= s;
    int i0 = 0;
    for (int e = 1; e < 8; e++) if (pr[e] > pr[i0]) i0 = e;
    int i1 = (i0 == 0) ? 1 : 0;
    for (int e = 0; e < 8; e++) if (e != i0 && pr[e] > pr[i1]) i1 = e;
    float sm = pr[i0] + pr[i1];
    for (int e = 0; e < 8; e++)
      we[(size_t)tok * 8 + e] = (e == i0) ? pr[i0] / sm : ((e == i1) ? pr[i1] / sm : 0.f);
  }
}

// -------- Routing: bucket tokens per expert (device-side counts) ----------
__global__ __launch_bounds__(256) void route_k(const float* __restrict__ we,
                                               int* __restrict__ cnt,
                                               int* __restrict__ gidx,
                                               float* __restrict__ gw){
  int tok = blockIdx.x * 256 + threadIdx.x;
#pragma unroll
  for (int e = 0; e < NEXP; e++){
    float w = we[(size_t)tok * NEXP + e];
    if (w > 0.f){
      int p = atomicAdd(&cnt[e], 1);
      gidx[e * N_TOK + p] = tok;
      gw[e * N_TOK + p] = w;
    }
  }
}

// -------- Transpose-convert: src f32 [R][C] -> dst bf16 [C][R] ------------
__global__ __launch_bounds__(256) void convT(const float* __restrict__ src,
                                             ushort_t* __restrict__ dst,
                                             int R, int C){
  __shared__ float tile[64][65];
  int r0 = blockIdx.y * 64, c0 = blockIdx.x * 64;
  int t = threadIdx.x;
  int tc = t & 15, tr = t >> 4;
#pragma unroll
  for (int i = 0; i < 4; i++){
    int r = tr + i * 16;
    float4 v = *(const float4*)&src[(size_t)(r0 + r) * C + c0 + tc * 4];
    tile[r][tc*4 + 0] = v.x; tile[r][tc*4 + 1] = v.y;
    tile[r][tc*4 + 2] = v.z; tile[r][tc*4 + 3] = v.w;
  }
  __syncthreads();
#pragma unroll
  for (int i = 0; i < 4; i++){
    int c = tr + i * 16;                     // output row = source col
    ushort4 o;
    o.x = f2bf(tile[tc*4 + 0][c]);
    o.y = f2bf(tile[tc*4 + 1][c]);
    o.z = f2bf(tile[tc*4 + 2][c]);
    o.w = f2bf(tile[tc*4 + 3][c]);
    *(ushort4*)&dst[(size_t)(c0 + c) * R + r0 + tc * 4] = o;
  }
}

// -------- MFMA bf16 expert GEMM (gather/scatter rows) ---------------------
// EPI 0: A rows gathered from gidx; store Obf[r][n] = bf16(gelu(v + bias[n]))
// EPI 1: A rows dense (h1e); scatter Of[gidx[r]][n] += gw[r] * (v + bias[n])
#define TBM 128
#define TBN 128
#define TBK 32
#define LDK 40   // padded LDS row stride in bf16 elems

template<int EPI>
__global__ __launch_bounds__(256) void moe_gemm(
    const ushort_t* __restrict__ A,   // bf16 [*][K]
    const ushort_t* __restrict__ BT,  // bf16 [N][K]
    const float* __restrict__ bias,   // [N]
    ushort_t* __restrict__ Obf,
    float* __restrict__ Of,
    const int* __restrict__ gidx,
    const float* __restrict__ gw,
    const int* __restrict__ cnt_e,
    int Nn, int K)
{
  int c = *cnt_e;
  int bm = blockIdx.y * TBM;
  if (bm >= c) return;
  int bn = blockIdx.x * TBN;
  __shared__ ushort_t As[TBM * LDK];
  __shared__ ushort_t Bs[TBN * LDK];
  int t = threadIdx.x;
  int lane = t & 63, wave = t >> 6;
  int wm = (wave & 1) * 64, wn = (wave >> 1) * 64;

  // staging: 2 passes x 256 threads x 16B; row = idx>>2, kc = (idx&3)*8
  int r0 = t >> 2, r1 = r0 + 64;
  int kc = (t & 3) * 8;
  size_t ga0, ga1;
  if (EPI == 0){
    int g0 = bm + r0, g1 = bm + r1;
    ga0 = (size_t)((g0 < c) ? gidx[g0] : gidx[bm]);
    ga1 = (size_t)((g1 < c) ? gidx[g1] : gidx[bm]);
  } else {
    ga0 = (size_t)(bm + r0); ga1 = (size_t)(bm + r1);
  }
  const ushort_t* a0p = A + ga0 * K + kc;
  const ushort_t* a1p = A + ga1 * K + kc;
  const ushort_t* b0p = BT + (size_t)(bn + r0) * K + kc;
  const ushort_t* b1p = BT + (size_t)(bn + r1) * K + kc;

  f32x4 acc[4][4] = {};
  int fm = lane & 15, fk = (lane >> 4) * 8;

  for (int k0 = 0; k0 < K; k0 += TBK){
    uint4 av0 = *(const uint4*)(a0p + k0);
    uint4 av1 = *(const uint4*)(a1p + k0);
    uint4 bv0 = *(const uint4*)(b0p + k0);
    uint4 bv1 = *(const uint4*)(b1p + k0);
    *(uint4*)&As[r0 * LDK + kc] = av0;
    *(uint4*)&As[r1 * LDK + kc] = av1;
    *(uint4*)&Bs[r0 * LDK + kc] = bv0;
    *(uint4*)&Bs[r1 * LDK + kc] = bv1;
    __syncthreads();
    short8 af[4], bfr[4];
#pragma unroll
    for (int mi = 0; mi < 4; mi++)
      af[mi] = *(const short8*)&As[(wm + mi*16 + fm) * LDK + fk];
#pragma unroll
    for (int nj = 0; nj < 4; nj++)
      bfr[nj] = *(const short8*)&Bs[(wn + nj*16 + fm) * LDK + fk];
#pragma unroll
    for (int mi = 0; mi < 4; mi++)
#pragma unroll
      for (int nj = 0; nj < 4; nj++)
        acc[mi][nj] = __builtin_amdgcn_mfma_f32_16x16x32_bf16(af[mi], bfr[nj], acc[mi][nj], 0, 0, 0);
    __syncthreads();
  }

  // epilogue: C/D layout col=lane&15, row=(lane>>4)*4+reg  [m89-verified]
#pragma unroll
  for (int mi = 0; mi < 4; mi++){
    int rowbase = bm + wm + mi*16 + (lane >> 4) * 4;
#pragma unroll
    for (int nj = 0; nj < 4; nj++){
      int n = bn + wn + nj*16 + (lane & 15);
      f32x4 v = acc[mi][nj];
#pragma unroll
      for (int rg = 0; rg < 4; rg++){
        int r = rowbase + rg;
        if (r < c){
          float val = v[rg] + bias[n];
          if (EPI == 0){
            Obf[(size_t)r * Nn + n] = f2bf(gelu_f(val));
          } else {
            int tok = gidx[r];
            Of[(size_t)tok * Nn + n] += gw[r] * val;
          }
        }
      }
    }
  }
}

// ---------------- Final: out = h + moe_acc (f32) --------------------------
__global__ __launch_bounds__(256) void final_k(const float* __restrict__ h,
                                               const float* __restrict__ acc,
                                               float* __restrict__ out){
  size_t i = (size_t)blockIdx.x * 256 + threadIdx.x;
  out[i] = h[i] + acc[i];
}

extern "C" void kernel_launch(void* const* d_in, const int* in_sizes, int n_in,
                              void* d_out, int out_size, void* d_ws, size_t ws_size,
                              hipStream_t stream){
  const float* x     = (const float*)d_in[0];
  const float* ln1w  = (const float*)d_in[1];
  const float* ln1b  = (const float*)d_in[2];
  const float* ln2w  = (const float*)d_in[3];
  const float* ln2b  = (const float*)d_in[4];
  const float* wqkv  = (const float*)d_in[5];
  const float* bqkv  = (const float*)d_in[6];
  const float* wo    = (const float*)d_in[7];
  const float* bo    = (const float*)d_in[8];
  const float* wgate = (const float*)d_in[9];
  const float* w1    = (const float*)d_in[10];
  const float* b1    = (const float*)d_in[11];
  const float* w2    = (const float*)d_in[12];
  const float* b2    = (const float*)d_in[13];

  // Workspace map (121 MB peak, proven available in round 4):
  //  [0,8)M    ln1 f32  -> accb f32 (after qkv GEMM)
  //  [8,32)M   qkv f32                (dead after ctx_k)
  //  [32,40)M  ctx f32                (dead after out-proj)
  //  [40,48)M  hbuf f32               (live to end)
  //  [48,56)M  ln2f f32               (dead after gate)
  //  [56,57)M  webuf / cnt / bucket idx+w
  //  [57,121)M sc f32 (dead after ctx_k) -> h1e bf16 16M | w1Te 8M | w2Te 8M | ln2bf 4M
  char* ws = (char*)d_ws;
  const size_t MB = 1024 * 1024;
  float*    ln1   = (float*)(ws + 0 * MB);
  float*    accb  = (float*)(ws + 0 * MB);
  float*    qkv   = (float*)(ws + 8 * MB);
  float*    ctx   = (float*)(ws + 32 * MB);
  float*    hbuf  = (float*)(ws + 40 * MB);
  float*    ln2f  = (float*)(ws + 48 * MB);
  float*    webuf = (float*)(ws + 56 * MB);                 // 64 KB
  int*      cnt   = (int*)  (ws + 56 * MB + 256 * 1024);    // 32 B
  int*      bidx  = (int*)  (ws + 56 * MB + 320 * 1024);    // 64 KB
  float*    bw    = (float*)(ws + 56 * MB + 448 * 1024);    // 64 KB
  float*    sc    = (float*)(ws + 57 * MB);
  ushort_t* h1e   = (ushort_t*)(ws + 57 * MB);              // 16 MB
  ushort_t* w1Te  = (ushort_t*)(ws + 73 * MB);              // 8 MB
  ushort_t* w2Te  = (ushort_t*)(ws + 81 * MB);              // 8 MB
  ushort_t* ln2bf = (ushort_t*)(ws + 89 * MB);              // 4 MB

  // ---- attention path (f32, unchanged from passing round) ----
  ln_k<false><<<N_TOK, 256, 0, stream>>>(x, ln1w, ln1b, ln1, nullptr);
  gemm128<0><<<dim3(D3 / BN, N_TOK / BM), 256, 0, stream>>>(
      ln1, wqkv, bqkv, qkv, nullptr, N_TOK, D3, DIM);
  scores_k<<<dim3(8, 8, 64), 256, 0, stream>>>(qkv, sc);
  softmax_k<<<64 * TT, 256, 0, stream>>>(sc);
  ctx_k<<<dim3(8, 64), 256, 0, stream>>>(sc, qkv, ctx);
  gemm128<1><<<dim3(DIM / BN, N_TOK / BM), 256, 0, stream>>>(
      ctx, wo, bo, hbuf, x, N_TOK, DIM, DIM);
  ln_k<true><<<N_TOK, 256, 0, stream>>>(hbuf, ln2w, ln2b, ln2f, ln2bf);
  gate_k<<<N_TOK / 4, 256, 0, stream>>>(ln2f, wgate, webuf);

  // ---- routed MoE (top-2, bf16 MFMA) ----
  hipMemsetAsync(cnt, 0, 32, stream);
  hipMemsetAsync(accb, 0, (size_t)N_TOK * DIM * 4, stream);
  route_k<<<N_TOK / 256, 256, 0, stream>>>(webuf, cnt, bidx, bw);
  for (int e = 0; e < NEXP; e++){
    // w1[e] f32 [DIM][HID] -> w1Te bf16 [HID][DIM]
    convT<<<dim3(HID / 64, DIM / 64), 256, 0, stream>>>(
        w1 + (size_t)e * DIM * HID, w1Te, DIM, HID);
    moe_gemm<0><<<dim3(HID / TBN, N_TOK / TBM), 256, 0, stream>>>(
        ln2bf, w1Te, b1 + (size_t)e * HID, h1e, nullptr,
        bidx + e * N_TOK, bw + e * N_TOK, cnt + e, HID, DIM);
    // w2[e] f32 [HID][DIM] -> w2Te bf16 [DIM][HID]
    convT<<<dim3(DIM / 64, HID / 64), 256, 0, stream>>>(
        w2 + (size_t)e * HID * DIM, w2Te, HID, DIM);
    moe_gemm<1><<<dim3(DIM / TBN, N_TOK / TBM), 256, 0, stream>>>(
        h1e, w2Te, b2 + (size_t)e * DIM, nullptr, accb,
        bidx + e * N_TOK, bw + e * N_TOK, cnt + e, DIM, HID);
  }
  final_k<<<(N_TOK * DIM) / 256, 256, 0, stream>>>(hbuf, accb, (float*)d_out);
}